// Round 1
// baseline (11551.810 us; speedup 1.0000x reference)
//
#include <hip/hip_runtime.h>

#define NB 64
#define TT 512
#define DD 1024
#define HH 1024

typedef __attribute__((ext_vector_type(4))) float f32x4;
typedef __attribute__((ext_vector_type(8))) short bf16x8;

static __device__ __forceinline__ unsigned short f2bf(float f) {
  unsigned u = __float_as_uint(f);
  unsigned r = (u + 0x7fffu + ((u >> 16) & 1u)) >> 16;
  return (unsigned short)r;
}
static __device__ __forceinline__ float bf2f(unsigned short u) {
  return __uint_as_float(((unsigned)u) << 16);
}

// ---------------------------------------------------------------- prep -----
// blocks [0,1024): transpose+split Wx (fp32 [k][n]) -> Wxh/Wxl (bf16 [n][k])
// blocks [1024,1280): h0 fp32 -> hbuf0 bf16
__global__ __launch_bounds__(256) void prep_kernel(
    const float* __restrict__ Wx, const float* __restrict__ h0,
    unsigned short* __restrict__ Wxh, unsigned short* __restrict__ Wxl,
    unsigned short* __restrict__ hbuf0) {
  __shared__ float tile[32][33];
  int b = blockIdx.x;
  int tid = threadIdx.x;
  if (b < 1024) {
    int tk = (b & 31) * 32;  // k tile origin
    int tn = (b >> 5) * 32;  // n tile origin
    int tx = tid & 31;
    int ty = tid >> 5;  // 0..7
#pragma unroll
    for (int ii = 0; ii < 4; ++ii) {
      int kk = ty + ii * 8;
      tile[kk][tx] = Wx[(tk + kk) * HH + tn + tx];  // coalesced over tx
    }
    __syncthreads();
#pragma unroll
    for (int ii = 0; ii < 4; ++ii) {
      int a = ty + ii * 8;            // n offset in tile
      float w = tile[tx][a];          // = Wx[tk+tx][tn+a]
      unsigned short hi = f2bf(w);
      float lo = w - bf2f(hi);
      Wxh[(tn + a) * DD + tk + tx] = hi;       // coalesced over tx
      Wxl[(tn + a) * DD + tk + tx] = f2bf(lo);
    }
  } else {
    int i = (b - 1024) * 256 + tid;  // 0..65535
    hbuf0[i] = f2bf(h0[i]);
  }
}

// ------------------------------------------------------------- xw GEMM -----
// out[M=32768][H=1024] = bf16(x) @ (Wxh + Wxl) + b     (fp32 accumulate)
#define BM 128
#define BN 128
#define BK 64

__global__ __launch_bounds__(256) void xw_gemm(
    const float* __restrict__ x, const unsigned short* __restrict__ Wxh,
    const unsigned short* __restrict__ Wxl, const float* __restrict__ bias,
    float* __restrict__ out) {
  __shared__ unsigned short As[BM * BK];  // [r][k] XOR-swizzled
  __shared__ unsigned short Bh[BN * BK];  // [c][k] XOR-swizzled
  __shared__ unsigned short Bl[BN * BK];

  int tid = threadIdx.x;
  int n0 = blockIdx.x * BN;
  int row0 = blockIdx.y * BM;
  int w = tid >> 6, lane = tid & 63;
  int wr = w >> 1, wc = w & 1;

  f32x4 acc[4][4];
#pragma unroll
  for (int m = 0; m < 4; ++m)
#pragma unroll
    for (int n = 0; n < 4; ++n) acc[m][n] = (f32x4)0.f;

  for (int kk = 0; kk < DD; kk += BK) {
    // ---- issue global loads into regs (overlaps with barrier wait) ----
    float4 av[8];
#pragma unroll
    for (int i = 0; i < 8; ++i) {
      int lin = tid + 256 * i;  // 0..2047
      int r = lin >> 4, kq = lin & 15;
      av[i] = *(const float4*)(x + (row0 + r) * DD + kk + kq * 4);
    }
    int4 bhv[4], blv[4];
#pragma unroll
    for (int i = 0; i < 4; ++i) {
      int lin = tid + 256 * i;  // 0..1023
      int c = lin >> 3, kb = lin & 7;
      bhv[i] = *(const int4*)(Wxh + (n0 + c) * DD + kk + kb * 8);
      blv[i] = *(const int4*)(Wxl + (n0 + c) * DD + kk + kb * 8);
    }
    __syncthreads();  // previous compute done reading LDS
    // ---- LDS writes (swizzled) ----
#pragma unroll
    for (int i = 0; i < 8; ++i) {
      int lin = tid + 256 * i;
      int r = lin >> 4, kq = lin & 15;
      uint2 u;
      u.x = (unsigned)f2bf(av[i].x) | ((unsigned)f2bf(av[i].y) << 16);
      u.y = (unsigned)f2bf(av[i].z) | ((unsigned)f2bf(av[i].w) << 16);
      *(uint2*)((char*)As + r * 128 + ((kq * 8) ^ ((r & 7) << 4))) = u;
    }
#pragma unroll
    for (int i = 0; i < 4; ++i) {
      int lin = tid + 256 * i;
      int c = lin >> 3, kb = lin & 7;
      int off = c * 128 + ((kb * 16) ^ ((c & 7) << 4));
      *(int4*)((char*)Bh + off) = bhv[i];
      *(int4*)((char*)Bl + off) = blv[i];
    }
    __syncthreads();
    // ---- MFMA ----
#pragma unroll
    for (int kt = 0; kt < 2; ++kt) {
      int krel2 = (kt * 32 + ((lane >> 4) << 3)) * 2;  // byte offset of k
      bf16x8 af[4], bhf[4], blf[4];
#pragma unroll
      for (int m = 0; m < 4; ++m) {
        int r = wr * 64 + m * 16 + (lane & 15);
        af[m] = *(const bf16x8*)((const char*)As + r * 128 +
                                 (krel2 ^ ((r & 7) << 4)));
      }
#pragma unroll
      for (int n = 0; n < 4; ++n) {
        int c = wc * 64 + n * 16 + (lane & 15);
        int off = c * 128 + (krel2 ^ ((c & 7) << 4));
        bhf[n] = *(const bf16x8*)((const char*)Bh + off);
        blf[n] = *(const bf16x8*)((const char*)Bl + off);
      }
#pragma unroll
      for (int m = 0; m < 4; ++m)
#pragma unroll
        for (int n = 0; n < 4; ++n) {
          acc[m][n] = __builtin_amdgcn_mfma_f32_16x16x32_bf16(af[m], bhf[n],
                                                              acc[m][n], 0, 0, 0);
          acc[m][n] = __builtin_amdgcn_mfma_f32_16x16x32_bf16(af[m], blf[n],
                                                              acc[m][n], 0, 0, 0);
        }
    }
    __syncthreads();  // compute done before next stage overwrites LDS
  }

  // ---- epilogue: + bias, store fp32 ----
#pragma unroll
  for (int n = 0; n < 4; ++n) {
    int col = n0 + wc * 64 + n * 16 + (lane & 15);
    float bv = bias[col];
#pragma unroll
    for (int m = 0; m < 4; ++m) {
      int rbase = row0 + wr * 64 + m * 16 + ((lane >> 4) << 2);
#pragma unroll
      for (int i = 0; i < 4; ++i)
        out[(rbase + i) * HH + col] = acc[m][n][i] + bv;
    }
  }
}

// ---------------------------------------------------------------- scan -----
// 4 batch groups x 32 col-WGs = 128 WGs; Wh hi/lo fragments live in VGPRs.
// h ping-pong (bf16) in ws; 32-WG flag barrier per step per group.
#define QCOLS 32
#define RROWS 16
#define CCOLS 32

__global__ __launch_bounds__(256) void rnn_scan(
    const float* __restrict__ Wh, float* __restrict__ out,
    unsigned short* __restrict__ hbuf, unsigned* __restrict__ flags) {
  int tid = threadIdx.x;
  int w = tid >> 6, lane = tid & 63;
  int p = blockIdx.x >> 5;  // batch group 0..3
  int q = blockIdx.x & 31;  // col group 0..31
  int n0 = p * RROWS;
  int c0 = q * CCOLS;

  __shared__ float red[4][2][16][16];

  // ---- load Wh fragments (hi+lo) into registers, MFMA B-layout ----
  bf16x8 whi[2][8], wlo[2][8];
#pragma unroll
  for (int ct = 0; ct < 2; ++ct) {
#pragma unroll
    for (int kt = 0; kt < 8; ++kt) {
      int c = c0 + ct * 16 + (lane & 15);
      int kb = w * 256 + kt * 32 + ((lane >> 4) << 3);
#pragma unroll
      for (int j = 0; j < 8; ++j) {
        float wf = Wh[(kb + j) * HH + c];
        unsigned short hi = f2bf(wf);
        float lo = wf - bf2f(hi);
        whi[ct][kt][j] = (short)hi;
        wlo[ct][kt][j] = (short)f2bf(lo);
      }
    }
  }

  // per-thread epilogue element mapping (2 outputs per thread)
  int orow[2], ocolg[2], obase[2];
#pragma unroll
  for (int e = 0; e < 2; ++e) {
    int o = tid + 256 * e;           // 0..511 over [ct][r][c]
    int ct = o >> 8, r = (o >> 4) & 15, c = o & 15;
    orow[e] = n0 + r;
    ocolg[e] = c0 + ct * 16 + c;
    obase[e] = orow[e] * (TT * HH) + ocolg[e];
  }

  int arow = n0 + (lane & 15);
  int abase = arow * HH + w * 256 + ((lane >> 4) << 3);

  // prefetch xw for t=0
  float xwc[2];
#pragma unroll
  for (int e = 0; e < 2; ++e) xwc[e] = out[obase[e]];

  for (int t = 0; t < TT; ++t) {
    const unsigned short* hp = hbuf + (t & 1) * (NB * HH);
    unsigned short* hn = hbuf + ((t + 1) & 1) * (NB * HH);

    // ---- A fragments from ping-pong h buffer ----
    const unsigned short* hrow = hp + abase;
    bf16x8 af[8];
#pragma unroll
    for (int kt = 0; kt < 8; ++kt) af[kt] = *(const bf16x8*)(hrow + kt * 32);

    f32x4 acc0 = (f32x4)0.f, acc1 = (f32x4)0.f;
#pragma unroll
    for (int kt = 0; kt < 8; ++kt) {
      acc0 = __builtin_amdgcn_mfma_f32_16x16x32_bf16(af[kt], whi[0][kt], acc0, 0, 0, 0);
      acc0 = __builtin_amdgcn_mfma_f32_16x16x32_bf16(af[kt], wlo[0][kt], acc0, 0, 0, 0);
      acc1 = __builtin_amdgcn_mfma_f32_16x16x32_bf16(af[kt], whi[1][kt], acc1, 0, 0, 0);
      acc1 = __builtin_amdgcn_mfma_f32_16x16x32_bf16(af[kt], wlo[1][kt], acc1, 0, 0, 0);
    }

    // ---- split-K reduce across the 4 waves ----
    int rr = (lane >> 4) << 2, cc = lane & 15;
#pragma unroll
    for (int i = 0; i < 4; ++i) {
      red[w][0][rr + i][cc] = acc0[i];
      red[w][1][rr + i][cc] = acc1[i];
    }
    __syncthreads();
#pragma unroll
    for (int e = 0; e < 2; ++e) {
      int o = tid + 256 * e;
      int ct = o >> 8, r = (o >> 4) & 15, c = o & 15;
      float s = red[0][ct][r][c] + red[1][ct][r][c] + red[2][ct][r][c] +
                red[3][ct][r][c];
      float hv = tanhf(s + xwc[e]);
      out[obase[e] + t * HH] = hv;
      hn[orow[e] * HH + ocolg[e]] = f2bf(hv);
    }

    // prefetch xw for t+1 (completes while we sit in the barrier)
    if (t + 1 < TT) {
#pragma unroll
      for (int e = 0; e < 2; ++e) xwc[e] = out[obase[e] + (t + 1) * HH];
    }

    // ---- inter-WG barrier (release -> count -> acquire) ----
    __threadfence();
    __syncthreads();
    if (tid == 0) {
      __hip_atomic_fetch_add(flags + p * 32, 1u, __ATOMIC_RELAXED,
                             __HIP_MEMORY_SCOPE_AGENT);
      unsigned target = (unsigned)(t + 1) * QCOLS;
      while (__hip_atomic_load(flags + p * 32, __ATOMIC_RELAXED,
                               __HIP_MEMORY_SCOPE_AGENT) < target)
        __builtin_amdgcn_s_sleep(2);
    }
    __syncthreads();
    __threadfence();
  }
}

// ------------------------------------------------------------- launch ------
extern "C" void kernel_launch(void* const* d_in, const int* in_sizes, int n_in,
                              void* d_out, int out_size, void* d_ws,
                              size_t ws_size, hipStream_t stream) {
  const float* x = (const float*)d_in[0];
  const float* h0 = (const float*)d_in[1];
  const float* Wx = (const float*)d_in[2];
  const float* Wh = (const float*)d_in[3];
  const float* b = (const float*)d_in[4];
  float* out = (float*)d_out;

  char* ws = (char*)d_ws;
  unsigned* flags = (unsigned*)ws;                                  // 512 B
  unsigned short* hbuf = (unsigned short*)(ws + 4096);              // 256 KB
  unsigned short* Wxh = (unsigned short*)(ws + 266240);             // 2 MB
  unsigned short* Wxl = (unsigned short*)(ws + 266240 + 2097152);   // 2 MB

  hipMemsetAsync(flags, 0, 512, stream);
  prep_kernel<<<1280, 256, 0, stream>>>(Wx, h0, Wxh, Wxl, hbuf);
  xw_gemm<<<dim3(8, 256), 256, 0, stream>>>(x, Wxh, Wxl, b, out);
  rnn_scan<<<128, 256, 0, stream>>>(Wh, out, hbuf, flags);
}

// Round 2
// 2936.814 us; speedup vs baseline: 3.9334x; 3.9334x over previous
//
#include <hip/hip_runtime.h>

#define NB 64
#define TT 512
#define DD 1024
#define HH 1024

typedef __attribute__((ext_vector_type(4))) float f32x4;
typedef __attribute__((ext_vector_type(8))) short bf16x8;

static __device__ __forceinline__ unsigned short f2bf(float f) {
  unsigned u = __float_as_uint(f);
  unsigned r = (u + 0x7fffu + ((u >> 16) & 1u)) >> 16;
  return (unsigned short)r;
}
static __device__ __forceinline__ float bf2f(unsigned short u) {
  return __uint_as_float(((unsigned)u) << 16);
}

// ---------------------------------------------------------------- prep -----
// blocks [0,1024): transpose+split Wx (fp32 [k][n]) -> Wxh/Wxl (bf16 [n][k])
// blocks [1024,1280): h0 fp32 -> hbuf0 bf16
__global__ __launch_bounds__(256) void prep_kernel(
    const float* __restrict__ Wx, const float* __restrict__ h0,
    unsigned short* __restrict__ Wxh, unsigned short* __restrict__ Wxl,
    unsigned short* __restrict__ hbuf0) {
  __shared__ float tile[32][33];
  int b = blockIdx.x;
  int tid = threadIdx.x;
  if (b < 1024) {
    int tk = (b & 31) * 32;  // k tile origin
    int tn = (b >> 5) * 32;  // n tile origin
    int tx = tid & 31;
    int ty = tid >> 5;  // 0..7
#pragma unroll
    for (int ii = 0; ii < 4; ++ii) {
      int kk = ty + ii * 8;
      tile[kk][tx] = Wx[(tk + kk) * HH + tn + tx];  // coalesced over tx
    }
    __syncthreads();
#pragma unroll
    for (int ii = 0; ii < 4; ++ii) {
      int a = ty + ii * 8;            // n offset in tile
      float w = tile[tx][a];          // = Wx[tk+tx][tn+a]
      unsigned short hi = f2bf(w);
      float lo = w - bf2f(hi);
      Wxh[(tn + a) * DD + tk + tx] = hi;       // coalesced over tx
      Wxl[(tn + a) * DD + tk + tx] = f2bf(lo);
    }
  } else {
    int i = (b - 1024) * 256 + tid;  // 0..65535
    hbuf0[i] = f2bf(h0[i]);
  }
}

// ------------------------------------------------------------- xw GEMM -----
// out[M=32768][H=1024] = bf16(x) @ (Wxh + Wxl) + b     (fp32 accumulate)
#define BM 128
#define BN 128
#define BK 64

__global__ __launch_bounds__(256) void xw_gemm(
    const float* __restrict__ x, const unsigned short* __restrict__ Wxh,
    const unsigned short* __restrict__ Wxl, const float* __restrict__ bias,
    float* __restrict__ out) {
  __shared__ unsigned short As[BM * BK];  // [r][k] XOR-swizzled
  __shared__ unsigned short Bh[BN * BK];  // [c][k] XOR-swizzled
  __shared__ unsigned short Bl[BN * BK];

  int tid = threadIdx.x;
  int n0 = blockIdx.x * BN;
  int row0 = blockIdx.y * BM;
  int w = tid >> 6, lane = tid & 63;
  int wr = w >> 1, wc = w & 1;

  f32x4 acc[4][4];
#pragma unroll
  for (int m = 0; m < 4; ++m)
#pragma unroll
    for (int n = 0; n < 4; ++n) acc[m][n] = (f32x4)0.f;

  for (int kk = 0; kk < DD; kk += BK) {
    // ---- issue global loads into regs (overlaps with barrier wait) ----
    float4 av[8];
#pragma unroll
    for (int i = 0; i < 8; ++i) {
      int lin = tid + 256 * i;  // 0..2047
      int r = lin >> 4, kq = lin & 15;
      av[i] = *(const float4*)(x + (row0 + r) * DD + kk + kq * 4);
    }
    int4 bhv[4], blv[4];
#pragma unroll
    for (int i = 0; i < 4; ++i) {
      int lin = tid + 256 * i;  // 0..1023
      int c = lin >> 3, kb = lin & 7;
      bhv[i] = *(const int4*)(Wxh + (n0 + c) * DD + kk + kb * 8);
      blv[i] = *(const int4*)(Wxl + (n0 + c) * DD + kk + kb * 8);
    }
    __syncthreads();  // previous compute done reading LDS
    // ---- LDS writes (swizzled) ----
#pragma unroll
    for (int i = 0; i < 8; ++i) {
      int lin = tid + 256 * i;
      int r = lin >> 4, kq = lin & 15;
      uint2 u;
      u.x = (unsigned)f2bf(av[i].x) | ((unsigned)f2bf(av[i].y) << 16);
      u.y = (unsigned)f2bf(av[i].z) | ((unsigned)f2bf(av[i].w) << 16);
      *(uint2*)((char*)As + r * 128 + ((kq * 8) ^ ((r & 7) << 4))) = u;
    }
#pragma unroll
    for (int i = 0; i < 4; ++i) {
      int lin = tid + 256 * i;
      int c = lin >> 3, kb = lin & 7;
      int off = c * 128 + ((kb * 16) ^ ((c & 7) << 4));
      *(int4*)((char*)Bh + off) = bhv[i];
      *(int4*)((char*)Bl + off) = blv[i];
    }
    __syncthreads();
    // ---- MFMA ----
#pragma unroll
    for (int kt = 0; kt < 2; ++kt) {
      int krel2 = (kt * 32 + ((lane >> 4) << 3)) * 2;  // byte offset of k
      bf16x8 af[4], bhf[4], blf[4];
#pragma unroll
      for (int m = 0; m < 4; ++m) {
        int r = wr * 64 + m * 16 + (lane & 15);
        af[m] = *(const bf16x8*)((const char*)As + r * 128 +
                                 (krel2 ^ ((r & 7) << 4)));
      }
#pragma unroll
      for (int n = 0; n < 4; ++n) {
        int c = wc * 64 + n * 16 + (lane & 15);
        int off = c * 128 + (krel2 ^ ((c & 7) << 4));
        bhf[n] = *(const bf16x8*)((const char*)Bh + off);
        blf[n] = *(const bf16x8*)((const char*)Bl + off);
      }
#pragma unroll
      for (int m = 0; m < 4; ++m)
#pragma unroll
        for (int n = 0; n < 4; ++n) {
          acc[m][n] = __builtin_amdgcn_mfma_f32_16x16x32_bf16(af[m], bhf[n],
                                                              acc[m][n], 0, 0, 0);
          acc[m][n] = __builtin_amdgcn_mfma_f32_16x16x32_bf16(af[m], blf[n],
                                                              acc[m][n], 0, 0, 0);
        }
    }
    __syncthreads();  // compute done before next stage overwrites LDS
  }

  // ---- epilogue: + bias, store fp32 ----
#pragma unroll
  for (int n = 0; n < 4; ++n) {
    int col = n0 + wc * 64 + n * 16 + (lane & 15);
    float bv = bias[col];
#pragma unroll
    for (int m = 0; m < 4; ++m) {
      int rbase = row0 + wr * 64 + m * 16 + ((lane >> 4) << 2);
#pragma unroll
      for (int i = 0; i < 4; ++i)
        out[(rbase + i) * HH + col] = acc[m][n][i] + bv;
    }
  }
}

// ---------------------------------------------------------------- scan -----
// 4 batch groups x 16 col-WGs (64 cols each) = 64 WGs; Wh hi/lo in VGPRs.
// h ping-pong (bf16, agent-scope atomics = L2-bypass coherent) in ws.
// Barrier: per-WG flag store + 16-lane vector poll. NO cache-wide fences.
#define RROWS 16
#define CCOLS 64
#define WGQ 16  // WGs per batch group

__global__ __launch_bounds__(256) void rnn_scan(
    const float* __restrict__ Wh, float* __restrict__ out,
    unsigned short* __restrict__ hbuf, unsigned* __restrict__ flags) {
  int tid = threadIdx.x;
  int w = tid >> 6, lane = tid & 63;
  int p = blockIdx.x >> 4;  // batch group 0..3
  int q = blockIdx.x & 15;  // col group 0..15
  int n0 = p * RROWS;
  int c0 = q * CCOLS;

  __shared__ float red[4][16][68];  // [wave][row][col], pad 68 -> conflict-free

  // ---- load Wh fragments (hi+lo) into registers, MFMA B-layout ----
  bf16x8 whi[4][8], wlo[4][8];
#pragma unroll
  for (int ct = 0; ct < 4; ++ct) {
#pragma unroll
    for (int kt = 0; kt < 8; ++kt) {
      int c = c0 + ct * 16 + (lane & 15);
      int kb = w * 256 + kt * 32 + ((lane >> 4) << 3);
#pragma unroll
      for (int j = 0; j < 8; ++j) {
        float wf = Wh[(kb + j) * HH + c];
        unsigned short hi = f2bf(wf);
        float lo = wf - bf2f(hi);
        whi[ct][kt][j] = (short)hi;
        wlo[ct][kt][j] = (short)f2bf(lo);
      }
    }
  }

  // epilogue mapping: thread -> (row, 4 consecutive cols)
  int erow = n0 + (tid >> 4);
  int ecol = c0 + ((tid & 15) << 2);
  int obase = erow * (TT * HH) + ecol;
  int hbase = erow * HH + ecol;

  // A-fragment base: row = n0 + (lane&15), k = w*256 + kt*32 + (lane>>4)*8
  int abase = (n0 + (lane & 15)) * HH + w * 256 + ((lane >> 4) << 3);

  // prefetch xw for t=0 (regular cached load; only this thread touches it)
  float4 xwc = *(const float4*)(out + obase);

  for (int t = 0; t < TT; ++t) {
    const unsigned short* hp = hbuf + (t & 1) * (NB * HH);
    unsigned short* hn = hbuf + ((t + 1) & 1) * (NB * HH);

    // ---- A fragments via agent-scope (L2-bypass) atomic loads ----
    const unsigned short* hrow = hp + abase;
    bf16x8 af[8];
#pragma unroll
    for (int kt = 0; kt < 8; ++kt) {
      union { unsigned long long u[2]; bf16x8 v; } pk;
      pk.u[0] = __hip_atomic_load(
          (const unsigned long long*)(hrow + kt * 32), __ATOMIC_RELAXED,
          __HIP_MEMORY_SCOPE_AGENT);
      pk.u[1] = __hip_atomic_load(
          (const unsigned long long*)(hrow + kt * 32 + 4), __ATOMIC_RELAXED,
          __HIP_MEMORY_SCOPE_AGENT);
      af[kt] = pk.v;
    }

    f32x4 acc[4];
#pragma unroll
    for (int ct = 0; ct < 4; ++ct) acc[ct] = (f32x4)0.f;
#pragma unroll
    for (int kt = 0; kt < 8; ++kt) {
#pragma unroll
      for (int ct = 0; ct < 4; ++ct) {
        acc[ct] = __builtin_amdgcn_mfma_f32_16x16x32_bf16(af[kt], whi[ct][kt],
                                                          acc[ct], 0, 0, 0);
        acc[ct] = __builtin_amdgcn_mfma_f32_16x16x32_bf16(af[kt], wlo[ct][kt],
                                                          acc[ct], 0, 0, 0);
      }
    }

    // ---- split-K reduce across the 4 waves ----
    int rr = (lane >> 4) << 2, cc = lane & 15;
#pragma unroll
    for (int ct = 0; ct < 4; ++ct)
#pragma unroll
      for (int i = 0; i < 4; ++i) red[w][rr + i][ct * 16 + cc] = acc[ct][i];
    __syncthreads();

    int r = tid >> 4, c4 = (tid & 15) << 2;
    float4 s = make_float4(0.f, 0.f, 0.f, 0.f);
#pragma unroll
    for (int ww = 0; ww < 4; ++ww) {
      float4 v = *(const float4*)&red[ww][r][c4];
      s.x += v.x; s.y += v.y; s.z += v.z; s.w += v.w;
    }
    float4 hv;
    hv.x = tanhf(s.x + xwc.x);
    hv.y = tanhf(s.y + xwc.y);
    hv.z = tanhf(s.z + xwc.z);
    hv.w = tanhf(s.w + xwc.w);

    // output (regular store; flushed at kernel end)
    *(float4*)(out + obase + t * HH) = hv;

    // h for next step: 4 bf16 packed -> one 8B agent-scope atomic store
    unsigned lo32 = (unsigned)f2bf(hv.x) | ((unsigned)f2bf(hv.y) << 16);
    unsigned hi32 = (unsigned)f2bf(hv.z) | ((unsigned)f2bf(hv.w) << 16);
    unsigned long long uu = ((unsigned long long)hi32 << 32) | lo32;
    __hip_atomic_store((unsigned long long*)(hn + hbase), uu, __ATOMIC_RELAXED,
                       __HIP_MEMORY_SCOPE_AGENT);

    if (t + 1 < TT) {
      // prefetch xw for t+1 (own element, regular load)
      xwc = *(const float4*)(out + obase + (t + 1) * HH);

      // ---- barrier: drain stores, publish own flag, poll all 16 ----
      __syncthreads();  // emits s_waitcnt vmcnt(0) per wave before s_barrier
      unsigned tgt = (unsigned)(t + 1);
      if (tid == 0)
        __hip_atomic_store(flags + p * 64 + q, tgt, __ATOMIC_RELAXED,
                           __HIP_MEMORY_SCOPE_AGENT);
      if (lane < WGQ) {
        const unsigned* fp2 = flags + p * 64 + lane;
        while (__hip_atomic_load(fp2, __ATOMIC_RELAXED,
                                 __HIP_MEMORY_SCOPE_AGENT) < tgt)
          __builtin_amdgcn_s_sleep(1);
      }
      asm volatile("" ::: "memory");  // keep h loads after the poll
    }
  }
}

// ------------------------------------------------------------- launch ------
extern "C" void kernel_launch(void* const* d_in, const int* in_sizes, int n_in,
                              void* d_out, int out_size, void* d_ws,
                              size_t ws_size, hipStream_t stream) {
  const float* x = (const float*)d_in[0];
  const float* h0 = (const float*)d_in[1];
  const float* Wx = (const float*)d_in[2];
  const float* Wh = (const float*)d_in[3];
  const float* b = (const float*)d_in[4];
  float* out = (float*)d_out;

  char* ws = (char*)d_ws;
  unsigned* flags = (unsigned*)ws;                                  // 1 KB
  unsigned short* hbuf = (unsigned short*)(ws + 4096);              // 256 KB
  unsigned short* Wxh = (unsigned short*)(ws + 266240);             // 2 MB
  unsigned short* Wxl = (unsigned short*)(ws + 266240 + 2097152);   // 2 MB

  hipMemsetAsync(flags, 0, 4096, stream);
  prep_kernel<<<1280, 256, 0, stream>>>(Wx, h0, Wxh, Wxl, hbuf);
  xw_gemm<<<dim3(8, 256), 256, 0, stream>>>(x, Wxh, Wxl, b, out);
  rnn_scan<<<64, 256, 0, stream>>>(Wh, out, hbuf, flags);
}